// Round 1
// baseline (69.126 us; speedup 1.0000x reference)
//
#include <hip/hip_runtime.h>
#include <math.h>

// Problem geometry (fixed by reference): x = [32, 3, 512, 512] fp32.
// Output = concat(gabor flat, x flat), both fp32.
constexpr int W_ = 512;
constexpr int H_ = 512;
constexpr int PLANE_ = W_ * H_;          // 262144
constexpr int VEC_PER_ROW = W_ / 4;      // 128
constexpr float S_ = 0.35355339059327373f;   // 1/(2*sqrt(2))

__global__ __launch_bounds__(256)
void gabor_kernel(const float* __restrict__ x,
                  float* __restrict__ gout,
                  float* __restrict__ xout,
                  int total_vec)
{
    int idx = blockIdx.x * blockDim.x + threadIdx.x;
    if (idx >= total_vec) return;

    const int w4    = idx & (VEC_PER_ROW - 1);   // vec4 index within row
    const int h     = (idx >> 7) & (H_ - 1);     // row
    const int plane = idx >> 16;                 // n*3 + c  (128*512 = 2^16)
    const int c     = plane % 3;                 // wave-uniform (plane uniform per wave)
    const int w0    = w4 << 2;

    const float* base = x + (size_t)plane * PLANE_ + (size_t)h * W_ + w0;

    // 6-wide register rows: [0]=left halo, [1..4]=center vec4, [5]=right halo
    float t_[6], m_[6], b_[6];

    // middle row (always in-bounds)
    {
        float4 v = *reinterpret_cast<const float4*>(base);
        m_[1] = v.x; m_[2] = v.y; m_[3] = v.z; m_[4] = v.w;
        m_[0] = (w4 > 0)               ? base[-1] : 0.0f;
        m_[5] = (w4 < VEC_PER_ROW - 1) ? base[4]  : 0.0f;
    }
    // top row (zero pad at h==0)
    if (h > 0) {
        const float* r = base - W_;
        float4 v = *reinterpret_cast<const float4*>(r);
        t_[1] = v.x; t_[2] = v.y; t_[3] = v.z; t_[4] = v.w;
        t_[0] = (w4 > 0)               ? r[-1] : 0.0f;
        t_[5] = (w4 < VEC_PER_ROW - 1) ? r[4]  : 0.0f;
    } else {
        #pragma unroll
        for (int i = 0; i < 6; ++i) t_[i] = 0.0f;
    }
    // bottom row (zero pad at h==H-1)
    if (h < H_ - 1) {
        const float* r = base + W_;
        float4 v = *reinterpret_cast<const float4*>(r);
        b_[1] = v.x; b_[2] = v.y; b_[3] = v.z; b_[4] = v.w;
        b_[0] = (w4 > 0)               ? r[-1] : 0.0f;
        b_[5] = (w4 < VEC_PER_ROW - 1) ? r[4]  : 0.0f;
    } else {
        #pragma unroll
        for (int i = 0; i < 6; ++i) b_[i] = 0.0f;
    }

    // per-channel normalization constants (wave-uniform branch)
    const float mean   = (c == 0) ? 0.485f         : (c == 1 ? 0.456f         : 0.406f);
    const float invstd = (c == 0) ? (1.0f/0.229f)  : (c == 1 ? (1.0f/0.224f)  : (1.0f/0.225f));

    float res[4];
    #pragma unroll
    for (int j = 0; j < 4; ++j) {
        // XLA conv = cross-correlation (no flip):
        // gx: KX = [[-S,0,S],[-1,0,1],[-S,0,S]]
        // gy: KY = [[ S,1,S],[ 0,0,0],[-S,-1,-S]]
        float gx = S_ * ((t_[j+2] - t_[j]) + (b_[j+2] - b_[j])) + (m_[j+2] - m_[j]);
        float gy = S_ * ((t_[j] + t_[j+2]) - (b_[j] + b_[j+2])) + (t_[j+1] - b_[j+1]);
        float den = m_[j+1] + 0.001f;
        // sqrt((gx/d)^2+(gy/d)^2) == sqrt(gx^2+gy^2)/d  (d > 0)
        float mag = sqrtf(gx * gx + gy * gy) / den;
        float g = atanf(mag) * (1.0f / 255.0f);
        res[j] = (g - mean) * invstd;
    }

    *reinterpret_cast<float4*>(gout + ((size_t)idx << 2)) =
        make_float4(res[0], res[1], res[2], res[3]);
    // passthrough copy of x from the already-loaded center row
    *reinterpret_cast<float4*>(xout + ((size_t)idx << 2)) =
        make_float4(m_[1], m_[2], m_[3], m_[4]);
}

extern "C" void kernel_launch(void* const* d_in, const int* in_sizes, int n_in,
                              void* d_out, int out_size, void* d_ws, size_t ws_size,
                              hipStream_t stream) {
    const float* x = (const float*)d_in[0];
    float* out = (float*)d_out;
    const int n_elem = in_sizes[0];          // 32*3*512*512 = 25165824
    const int total_vec = n_elem / 4;        // 6291456
    float* gout = out;                       // gabor output
    float* xout = out + n_elem;              // x passthrough

    const int block = 256;
    const int grid = (total_vec + block - 1) / block;   // 24576 blocks
    gabor_kernel<<<grid, block, 0, stream>>>(x, gout, xout, total_vec);
}

// Round 3
// 66.613 us; speedup vs baseline: 1.0377x; 1.0377x over previous
//
#include <hip/hip_runtime.h>
#include <math.h>

// x = [32, 3, 512, 512] fp32. Output = concat(gabor flat, x flat), fp32.
constexpr int W_ = 512;
constexpr int H_ = 512;
constexpr int PLANE_ = W_ * H_;              // 262144
constexpr float S_ = 0.35355339059327373f;   // 1/(2*sqrt(2))

typedef float f32x4 __attribute__((ext_vector_type(4)));  // native vec for builtins

// One pixel of the fused op. XLA conv = cross-correlation (no flip).
//   KX = [[-S,0,S],[-1,0,1],[-S,0,S]],  KY = [[S,1,S],[0,0,0],[-S,-1,-S]]
// sqrt((gx/d)^2+(gy/d)^2) == sqrt(gx^2+gy^2)/d  (d = x+0.001 > 0)
__device__ __forceinline__ float gab(float tl, float tc, float tr,
                                     float ml, float mc, float mr,
                                     float bl, float bc, float br,
                                     float mean, float invstd)
{
    float gx = S_ * ((tr - tl) + (br - bl)) + (mr - ml);
    float gy = S_ * ((tl + tr) - (bl + br)) + (tc - bc);
    float den = mc + 0.001f;
    float mag = sqrtf(gx * gx + gy * gy) * __builtin_amdgcn_rcpf(den);
    float g = atanf(mag) * (1.0f / 255.0f);
    return (g - mean) * invstd;
}

// 8-wide x 2-row tile per thread. One wave (64 lanes) covers one full
// row-pair of a plane; a 256-thread block covers 4 consecutive row-pairs
// (8 contiguous rows) -> strong L1 reuse of the vertical halo.
__global__ __launch_bounds__(256)
void gabor_kernel(const float* __restrict__ x,
                  float* __restrict__ gout,
                  float* __restrict__ xout)
{
    const int lane  = threadIdx.x & 63;
    const int wv    = threadIdx.x >> 6;          // 0..3
    const int bid   = blockIdx.x;
    const int plane = bid >> 6;                  // 96 planes, 64 blocks/plane
    const int rpg   = bid & 63;
    const int hp    = (rpg << 2) | wv;           // row-pair index 0..255
    const int h0    = hp << 1;                   // even output row
    const int w0    = lane << 3;                 // 8-wide chunk start

    const size_t pbase = (size_t)plane * PLANE_;
    const float* row0 = x + pbase + (size_t)h0 * W_ + w0;
    const float* row1 = row0 + W_;

    // rows: r0 = h0-1 (pad), r1 = h0, r2 = h0+1, r3 = h0+2 (pad)
    // layout: [0]=left halo, [1..8]=center 8, [9]=right halo
    float r0[10], r1[10], r2[10], r3[10];

#define LOADROW(dst, r)                                             \
    {                                                               \
        f32x4 a = *reinterpret_cast<const f32x4*>(r);               \
        f32x4 b = *reinterpret_cast<const f32x4*>((r) + 4);         \
        dst[1] = a.x; dst[2] = a.y; dst[3] = a.z; dst[4] = a.w;     \
        dst[5] = b.x; dst[6] = b.y; dst[7] = b.z; dst[8] = b.w;     \
        dst[0] = (lane > 0)  ? (r)[-1] : 0.0f;                      \
        dst[9] = (lane < 63) ? (r)[8]  : 0.0f;                      \
    }

    LOADROW(r1, row0)
    LOADROW(r2, row1)
    if (h0 > 0) {
        LOADROW(r0, row0 - W_)
    } else {
        #pragma unroll
        for (int i = 0; i < 10; ++i) r0[i] = 0.0f;
    }
    if (h0 < H_ - 2) {
        LOADROW(r3, row1 + W_)
    } else {
        #pragma unroll
        for (int i = 0; i < 10; ++i) r3[i] = 0.0f;
    }
#undef LOADROW

    const int c = plane % 3;   // wave-uniform
    const float mean   = (c == 0) ? 0.485f        : (c == 1 ? 0.456f        : 0.406f);
    const float invstd = (c == 0) ? (1.0f/0.229f) : (c == 1 ? (1.0f/0.224f) : (1.0f/0.225f));

    float ga[8], gb[8];
    #pragma unroll
    for (int j = 1; j <= 8; ++j) {
        ga[j-1] = gab(r0[j-1], r0[j], r0[j+1],
                      r1[j-1], r1[j], r1[j+1],
                      r2[j-1], r2[j], r2[j+1], mean, invstd);
    }
    #pragma unroll
    for (int j = 1; j <= 8; ++j) {
        gb[j-1] = gab(r1[j-1], r1[j], r1[j+1],
                      r2[j-1], r2[j], r2[j+1],
                      r3[j-1], r3[j], r3[j+1], mean, invstd);
    }

    const size_t o0 = pbase + (size_t)h0 * W_ + w0;
    const size_t o1 = o0 + W_;

#define NTSTORE(p, a, b, cc, d)                                     \
    {                                                               \
        f32x4 v_; v_.x = (a); v_.y = (b); v_.z = (cc); v_.w = (d);  \
        __builtin_nontemporal_store(v_, reinterpret_cast<f32x4*>(p)); \
    }

    // gabor output (streamed, never re-read -> nontemporal)
    NTSTORE(gout + o0,     ga[0], ga[1], ga[2], ga[3])
    NTSTORE(gout + o0 + 4, ga[4], ga[5], ga[6], ga[7])
    NTSTORE(gout + o1,     gb[0], gb[1], gb[2], gb[3])
    NTSTORE(gout + o1 + 4, gb[4], gb[5], gb[6], gb[7])
    // x passthrough from already-loaded center rows
    NTSTORE(xout + o0,     r1[1], r1[2], r1[3], r1[4])
    NTSTORE(xout + o0 + 4, r1[5], r1[6], r1[7], r1[8])
    NTSTORE(xout + o1,     r2[1], r2[2], r2[3], r2[4])
    NTSTORE(xout + o1 + 4, r2[5], r2[6], r2[7], r2[8])
#undef NTSTORE
}

extern "C" void kernel_launch(void* const* d_in, const int* in_sizes, int n_in,
                              void* d_out, int out_size, void* d_ws, size_t ws_size,
                              hipStream_t stream) {
    const float* x = (const float*)d_in[0];
    float* out = (float*)d_out;
    const int n_elem = in_sizes[0];          // 25165824
    float* gout = out;
    float* xout = out + n_elem;

    // 96 planes x 64 blocks/plane; block = 4 waves = 4 row-pairs
    const int grid = 96 * 64;                // 6144
    gabor_kernel<<<grid, 256, 0, stream>>>(x, gout, xout);
}